// Round 1
// baseline (5520.081 us; speedup 1.0000x reference)
//
#include <hip/hip_runtime.h>
#include <hip/hip_bf16.h>
#include <math.h>

typedef __hip_bfloat16 bf16;
typedef __attribute__((ext_vector_type(8))) short short8b;
typedef __attribute__((ext_vector_type(8))) __bf16 bf16x8;
typedef __attribute__((ext_vector_type(4))) float f32x4;

#define SCALE_F 0.04419417382415922f  // 1/sqrt(512)

// ---- MFMA wrapper tolerant of either builtin signature (v8i16 or v8bf16) ----
template <typename V>
static __device__ inline auto mfma_try(V a, V b, f32x4 c, int)
    -> decltype(__builtin_amdgcn_mfma_f32_16x16x32_bf16(a, b, c, 0, 0, 0)) {
  return __builtin_amdgcn_mfma_f32_16x16x32_bf16(a, b, c, 0, 0, 0);
}
template <typename V>
static __device__ inline auto mfma_try(V a, V b, f32x4 c, long)
    -> decltype(__builtin_amdgcn_mfma_f32_16x16x32_bf16(
        __builtin_bit_cast(bf16x8, a), __builtin_bit_cast(bf16x8, b), c, 0, 0, 0)) {
  return __builtin_amdgcn_mfma_f32_16x16x32_bf16(
      __builtin_bit_cast(bf16x8, a), __builtin_bit_cast(bf16x8, b), c, 0, 0, 0);
}
static __device__ inline f32x4 MFMA(short8b a, short8b b, f32x4 c) {
  return mfma_try(a, b, c, 0);
}

static __device__ inline short8b ldb8(const bf16* p) {
  return *reinterpret_cast<const short8b*>(p);
}
static __device__ inline float b2f(bf16 v) { return __bfloat162float(v); }
static __device__ inline bf16 f2b(float v) { return __float2bfloat16(v); }
static __device__ inline float s2f(short s) {
  unsigned u = ((unsigned)(unsigned short)s) << 16;
  return __builtin_bit_cast(float, u);
}
static __device__ inline float sigm(float x) { return 1.f / (1.f + expf(-x)); }

// ---- device-scope spin barrier (all blocks co-resident: 64 blocks on 256 CUs) ----
static __device__ inline void gbar(unsigned* cnt, unsigned target) {
  __syncthreads();
  if (threadIdx.x == 0) {
    __threadfence();
    __hip_atomic_fetch_add(cnt, 1u, __ATOMIC_RELAXED, __HIP_MEMORY_SCOPE_AGENT);
    while (__hip_atomic_load(cnt, __ATOMIC_RELAXED, __HIP_MEMORY_SCOPE_AGENT) < target) {
      __builtin_amdgcn_s_sleep(4);
    }
    __threadfence();
  }
  __syncthreads();
}

// =======================  generic MFMA GEMM  =======================
// C[M,N] = A[M,K] @ B[N,K]^T (+bias), A/B bf16 row-major K-contig, fp32 accum.
// block = 256 thr = 4 waves (2x2), tile 128x128, wave tile 64x64 (4x4 frags).
template <typename OutT, bool HAS_BIAS>
__global__ __launch_bounds__(256) void gemm_k(
    const bf16* __restrict__ A, const bf16* __restrict__ Bw,
    OutT* __restrict__ C, const float* __restrict__ bias,
    int M, int N, int K) {
  const int lane = threadIdx.x & 63;
  const int wid = threadIdx.x >> 6;
  const int m0 = blockIdx.y * 128 + (wid >> 1) * 64;
  const int n0 = blockIdx.x * 128 + (wid & 1) * 64;
  const int lr = lane & 15;
  const int lk = (lane >> 4) * 8;
  f32x4 acc[4][4];
#pragma unroll
  for (int i = 0; i < 4; ++i)
#pragma unroll
    for (int j = 0; j < 4; ++j) acc[i][j] = (f32x4){0.f, 0.f, 0.f, 0.f};
  const bf16* Ap = A + (size_t)(m0 + lr) * K + lk;
  const bf16* Bp = Bw + (size_t)(n0 + lr) * K + lk;
  for (int k0 = 0; k0 < K; k0 += 32) {
    short8b av[4], bv[4];
#pragma unroll
    for (int i = 0; i < 4; ++i) av[i] = ldb8(Ap + (size_t)i * 16 * K + k0);
#pragma unroll
    for (int i = 0; i < 4; ++i) bv[i] = ldb8(Bp + (size_t)i * 16 * K + k0);
#pragma unroll
    for (int mi = 0; mi < 4; ++mi)
#pragma unroll
      for (int ni = 0; ni < 4; ++ni)
        acc[mi][ni] = MFMA(av[mi], bv[ni], acc[mi][ni]);
  }
  const int rb = (lane >> 4) * 4;
#pragma unroll
  for (int mi = 0; mi < 4; ++mi) {
#pragma unroll
    for (int r = 0; r < 4; ++r) {
      const int row = m0 + mi * 16 + rb + r;
#pragma unroll
      for (int ni = 0; ni < 4; ++ni) {
        const int col = n0 + ni * 16 + lr;
        float v = acc[mi][ni][r];
        if (HAS_BIAS) v += bias[col];
        if constexpr (sizeof(OutT) == 2) {
          C[(size_t)row * N + col] = f2b(v);
        } else {
          C[(size_t)row * N + col] = v;
        }
      }
    }
  }
}

// =======================  prep kernels  =======================
__global__ void k_xg(const float* __restrict__ emb, const int* __restrict__ trg,
                     bf16* __restrict__ xg) {
  const int i = blockIdx.x * 256 + threadIdx.x;   // 2048*512 exact
  const int r = i >> 9, e = i & 511;
  const int t = r >> 5, b = r & 31;
  const int tok = trg[b * 64 + t];
  xg[i] = f2b(emb[(size_t)tok * 512 + e]);
}

__global__ void k_srcb(const float* __restrict__ s, bf16* __restrict__ d) {
  const int i = blockIdx.x * 256 + threadIdx.x;   // 2048*1024 exact
  d[i] = f2b(s[i]);
}

__global__ void k_fcw(const float* __restrict__ s, bf16* __restrict__ d) {
  const size_t stride = (size_t)gridDim.x * blockDim.x;
  for (size_t i = blockIdx.x * (size_t)blockDim.x + threadIdx.x;
       i < (size_t)32000 * 1024; i += stride)
    d[i] = f2b(s[i]);
}

__global__ void k_wpack(const float* __restrict__ fWih, const float* __restrict__ fWhh,
                        const float* __restrict__ bWih, const float* __restrict__ bWhh,
                        const float* __restrict__ fattW, const float* __restrict__ battW,
                        const float* __restrict__ bahW, const float* __restrict__ fahW,
                        bf16* Wxf, bf16* Wxb, bf16* Wrecf, bf16* Wrecb,
                        bf16* attWtf, bf16* attWtb, bf16* ahW2f, bf16* ahW2b,
                        float* Wh1f, float* Wh1b) {
  const int stride = gridDim.x * blockDim.x;
  const int i0 = blockIdx.x * blockDim.x + threadIdx.x;
  for (int i = i0; i < 2048 * 512; i += stride) {        // Wih x-slice
    const int gc = i >> 9, k = i & 511;
    Wxf[i] = f2b(fWih[(size_t)gc * 1024 + k]);
    Wxb[i] = f2b(bWih[(size_t)gc * 1024 + k]);
  }
  for (int i = i0; i < 2048 * 1024; i += stride) {       // [Wih_h | Whh]
    const int gc = i >> 10, k = i & 1023;
    float vf, vb;
    if (k < 512) { vf = fWih[(size_t)gc * 1024 + 512 + k]; vb = bWih[(size_t)gc * 1024 + 512 + k]; }
    else         { vf = fWhh[(size_t)gc * 512 + k - 512]; vb = bWhh[(size_t)gc * 512 + k - 512]; }
    Wrecf[i] = f2b(vf); Wrecb[i] = f2b(vb);
  }
  for (int i = i0; i < 512 * 1024; i += stride) {        // attW transpose
    const int j = i >> 10, d = i & 1023;
    attWtf[i] = f2b(fattW[(size_t)d * 512 + j]);
    attWtb[i] = f2b(battW[(size_t)d * 512 + j]);
  }
  for (int i = i0; i < 512 * 1024; i += stride) {        // ah_W ct-slice (swapped: fwd uses bah)
    const int o = i >> 10, d = i & 1023;
    ahW2f[i] = f2b(bahW[(size_t)o * 1536 + 512 + d]);
    ahW2b[i] = f2b(fahW[(size_t)o * 1536 + 512 + d]);
  }
  for (int i = i0; i < 512 * 512; i += stride) {         // ah_W h-slice fp32
    const int o = i >> 9, k = i & 511;
    Wh1f[i] = bahW[(size_t)o * 1536 + k];
    Wh1b[i] = fahW[(size_t)o * 1536 + k];
  }
}

__global__ void k_c0(const float* __restrict__ src, const float* __restrict__ fb,
                     const float* __restrict__ bb, float* __restrict__ c0f,
                     float* __restrict__ c0b) {
  const int r = blockIdx.x;
  const int tid = threadIdx.x;
  float pf = 0.f, pb = 0.f;
  for (int d = tid; d < 1024; d += 256) {
    const float s = src[(size_t)r * 1024 + d];
    pf += s * fb[d];
    pb += s * bb[d];
  }
#pragma unroll
  for (int d = 1; d < 64; d <<= 1) { pf += __shfl_xor(pf, d); pb += __shfl_xor(pb, d); }
  __shared__ float rf[4], rb2[4];
  if ((tid & 63) == 0) { rf[tid >> 6] = pf; rb2[tid >> 6] = pb; }
  __syncthreads();
  if (tid == 0) {
    c0f[r] = (rf[0] + rf[1] + rf[2] + rf[3]) * SCALE_F;
    c0b[r] = (rb2[0] + rb2[1] + rb2[2] + rb2[3]) * SCALE_F;
  }
}

// state layout per dir: st[b][1536] = [hhat(512) | h_slot0(512) | h_slot1(512)], bf16
// cell state: cst[j][32] fp32 (k-major, block-private per j-slice)
__global__ void k_init(const float* __restrict__ feed, const float* __restrict__ hid,
                       bf16* st0, bf16* st1, float* cst0, float* cst1) {
  const int i = blockIdx.x * 256 + threadIdx.x;   // 32*512 exact
  const int b = i >> 9, k = i & 511;
  st0[(size_t)b * 1536 + k] = f2b(feed[k]);
  st0[(size_t)b * 1536 + 512 + k] = f2b(hid[k]);
  cst0[k * 32 + b] = hid[512 + k];
  st1[(size_t)b * 1536 + k] = f2b(feed[512 + k]);
  st1[(size_t)b * 1536 + 512 + k] = f2b(hid[1024 + k]);
  cst1[k * 32 + b] = hid[1536 + k];
}

// =======================  sequential scan  =======================
struct ScanP {
  const bf16* Wrec[2]; const bf16* Xp[2]; const bf16* Af[2]; const bf16* Bm[2];
  const float* Wh1[2]; const float* bih[2]; const float* bhh[2];
  const float* c0[2]; const float* ahb[2]; const float* mask;
  bf16* st[2]; float* cst[2]; bf16* hcat; unsigned* bar;
};

__global__ __launch_bounds__(256) void scan_k(ScanP P) {
  const int blk = blockIdx.x;     // 64 blocks
  const int dir = blk >> 5;       // 0 fwd, 1 bwd
  const int g = blk & 31;         // PhaseA: j-slice; PhaseB: batch index
  const int tid = threadIdx.x;
  const int lane = tid & 63;
  const int wv = tid >> 6;

  const bf16* __restrict__ Wrec = P.Wrec[dir];
  const bf16* __restrict__ Xp = P.Xp[dir];
  const bf16* __restrict__ Af = P.Af[dir];
  const bf16* __restrict__ Bm = P.Bm[dir];
  const float* __restrict__ Wh1 = P.Wh1[dir];
  const float* __restrict__ bihp = P.bih[dir];
  const float* __restrict__ bhhp = P.bhh[dir];
  const float* __restrict__ c0v = P.c0[dir];
  const float* __restrict__ ahbp = P.ahb[dir];
  bf16* __restrict__ st = P.st[dir];
  float* __restrict__ cst = P.cst[dir];

  __shared__ float gl[4][16][33];
  __shared__ float h_lds[512];
  __shared__ float w_lds[64];
  __shared__ float p_lds[64];

  unsigned ep = 0;

  for (int t = 0; t < 64; ++t) {
    // ---------- Phase A: gates (MFMA) + LSTM cell, block owns j in [g*16, g*16+16) ----------
    {
      const int gate = wv;                   // wave 0..3 -> i,f,g,o
      const int lr = lane & 15;
      const int kb = lane >> 4;
      const int koff = kb * 8;
      const int gc = gate * 512 + g * 16 + lr;
      const bf16* Brow = Wrec + (size_t)gc * 1024;
      const bf16* A0 = st + (size_t)lr * 1536;
      const bf16* A1 = st + (size_t)(lr + 16) * 1536;
      const int hoff = 512 + (t & 1) * 512;  // read slot = t&1
      f32x4 ac0 = (f32x4){0.f, 0.f, 0.f, 0.f};
      f32x4 ac1 = (f32x4){0.f, 0.f, 0.f, 0.f};
#pragma unroll
      for (int ks = 0; ks < 16; ++ks) {      // hhat part (k 0..511)
        const int k = ks * 32 + koff;
        const short8b bv = ldb8(Brow + k);
        ac0 = MFMA(ldb8(A0 + k), bv, ac0);
        ac1 = MFMA(ldb8(A1 + k), bv, ac1);
      }
#pragma unroll
      for (int ks = 0; ks < 16; ++ks) {      // h part (k 512..1023)
        const int k = ks * 32 + koff;
        const short8b bv = ldb8(Brow + 512 + k);
        ac0 = MFMA(ldb8(A0 + hoff + k), bv, ac0);
        ac1 = MFMA(ldb8(A1 + hoff + k), bv, ac1);
      }
      const int tcol = dir ? (63 - t) : t;
      const float bsum = bihp[gc] + bhhp[gc];
      const bf16* xpc = Xp + (size_t)gc * 2048 + tcol * 32;
#pragma unroll
      for (int r = 0; r < 4; ++r) {
        const int brow = kb * 4 + r;         // D: row=(lane>>4)*4+reg, col=lane&15
        gl[gate][lr][brow] = ac0[r] + b2f(xpc[brow]) + bsum;
        gl[gate][lr][brow + 16] = ac1[r] + b2f(xpc[brow + 16]) + bsum;
      }
    }
    __syncthreads();
    {
      const int b = tid & 31;
      const int parW = 1 - (t & 1);          // write slot
#pragma unroll
      for (int it = 0; it < 2; ++it) {
        const int jl = (tid >> 5) + it * 8;
        const int j = g * 16 + jl;
        const float gi = gl[0][jl][b];
        const float gf = gl[1][jl][b];
        const float gg = gl[2][jl][b];
        const float go = gl[3][jl][b];
        float cn = sigm(gf) * cst[j * 32 + b] + sigm(gi) * tanhf(gg);
        float hn = sigm(go) * tanhf(cn);
        if (dir) {
          const float m = P.mask[b * 64 + (63 - t)];
          hn *= m; cn *= m;
        }
        cst[j * 32 + b] = cn;
        st[(size_t)b * 1536 + 512 + parW * 512 + j] = f2b(hn);
      }
    }
    ++ep; gbar(P.bar, ep * 64u);

    // ---------- Phase B: attention + hhat for batch b = g ----------
    {
      const int hre = 512 + (1 - (t & 1)) * 512;
      const bf16* hrow = st + (size_t)g * 1536 + hre;
      for (int k = tid; k < 512; k += 256) h_lds[k] = b2f(hrow[k]);
    }
    __syncthreads();
    {
      const int s = tid >> 2, q = tid & 3;
      const bf16* arow = Af + (size_t)(g * 64 + s) * 512 + q * 128;
      float part = 0.f;
#pragma unroll 4
      for (int k8 = 0; k8 < 128; k8 += 8) {
        const short8b v = ldb8(arow + k8);
#pragma unroll
        for (int e = 0; e < 8; ++e) part += h_lds[q * 128 + k8 + e] * s2f(v[e]);
      }
      part += __shfl_xor(part, 1);
      part += __shfl_xor(part, 2);
      if (q == 0) w_lds[s] = part * SCALE_F + c0v[g * 64 + s];
    }
    __syncthreads();
    if (tid < 64) {
      const float v = w_lds[tid];
      float mx = v;
#pragma unroll
      for (int d = 1; d < 64; d <<= 1) mx = fmaxf(mx, __shfl_xor(mx, d));
      const float e = expf(v - mx);
      float sm = e;
#pragma unroll
      for (int d = 1; d < 64; d <<= 1) sm += __shfl_xor(sm, d);
      p_lds[tid] = e / sm;
    }
    __syncthreads();
    {
#pragma unroll
      for (int it = 0; it < 2; ++it) {
        const int o = tid + it * 256;
        float acc = ahbp[o];
        const float* wrow = Wh1 + (size_t)o * 512;
#pragma unroll 2
        for (int k = 0; k < 512; k += 4) {
          const float4 w4 = *reinterpret_cast<const float4*>(wrow + k);
          acc += h_lds[k] * w4.x + h_lds[k + 1] * w4.y + h_lds[k + 2] * w4.z + h_lds[k + 3] * w4.w;
        }
        const bf16* bmc = Bm + (size_t)(g * 64) * 512 + o;
        float acc2 = 0.f;
#pragma unroll 4
        for (int s2 = 0; s2 < 64; ++s2) acc2 += p_lds[s2] * b2f(bmc[(size_t)s2 * 512]);
        const float hh = tanhf(acc + acc2);
        st[(size_t)g * 1536 + o] = f2b(hh);                                   // hhat slot
        if (dir == 0) {
          P.hcat[(size_t)(g * 64 + t) * 1024 + o] = f2b(hh);                  // f_out[:, t]
        } else if (t >= 2) {
          P.hcat[(size_t)(g * 64 + t - 2) * 1024 + 512 + o] = f2b(hh);        // b_shift
        }
      }
    }
    ++ep; gbar(P.bar, ep * 64u);
  }
}

// =======================  host  =======================
extern "C" void kernel_launch(void* const* d_in, const int* in_sizes, int n_in,
                              void* d_out, int out_size, void* d_ws, size_t ws_size,
                              hipStream_t stream) {
  (void)in_sizes; (void)n_in; (void)out_size; (void)ws_size;
  const float* src  = (const float*)d_in[0];
  const int*   trg  = (const int*)d_in[1];
  const float* mask = (const float*)d_in[2];
  const float* emb  = (const float*)d_in[3];
  const float* fWih = (const float*)d_in[4];
  const float* fWhh = (const float*)d_in[5];
  const float* fbih = (const float*)d_in[6];
  const float* fbhh = (const float*)d_in[7];
  const float* bWih = (const float*)d_in[8];
  const float* bWhh = (const float*)d_in[9];
  const float* bbih = (const float*)d_in[10];
  const float* bbhh = (const float*)d_in[11];
  const float* fattW = (const float*)d_in[12];
  const float* fattb = (const float*)d_in[13];
  const float* battW = (const float*)d_in[14];
  const float* battb = (const float*)d_in[15];
  const float* fahW = (const float*)d_in[16];
  const float* fahb = (const float*)d_in[17];
  const float* bahW = (const float*)d_in[18];
  const float* bahb = (const float*)d_in[19];
  const float* fcW  = (const float*)d_in[20];
  const float* fcb  = (const float*)d_in[21];
  const float* feed = (const float*)d_in[22];
  const float* hid  = (const float*)d_in[23];

  char* wsp = (char*)d_ws;
  size_t off = 0;
  auto alloc = [&](size_t bytes) -> void* {
    void* p = wsp + off;
    off += (bytes + 255) & ~(size_t)255;
    return p;
  };
  unsigned* bar = (unsigned*)alloc(256);
  bf16* hcat = (bf16*)alloc((size_t)2048 * 1024 * 2);
  const size_t zero_bytes = off;                 // bar + hcat zeroed per launch
  bf16* xg    = (bf16*)alloc((size_t)2048 * 512 * 2);
  bf16* srcb  = (bf16*)alloc((size_t)2048 * 1024 * 2);
  bf16* fcWb  = (bf16*)alloc((size_t)32000 * 1024 * 2);
  bf16* Wxf   = (bf16*)alloc((size_t)2048 * 512 * 2);
  bf16* Wxb   = (bf16*)alloc((size_t)2048 * 512 * 2);
  bf16* Wrecf = (bf16*)alloc((size_t)2048 * 1024 * 2);
  bf16* Wrecb = (bf16*)alloc((size_t)2048 * 1024 * 2);
  bf16* attWtf = (bf16*)alloc((size_t)512 * 1024 * 2);
  bf16* attWtb = (bf16*)alloc((size_t)512 * 1024 * 2);
  bf16* ahW2f = (bf16*)alloc((size_t)512 * 1024 * 2);
  bf16* ahW2b = (bf16*)alloc((size_t)512 * 1024 * 2);
  float* Wh1f = (float*)alloc((size_t)512 * 512 * 4);
  float* Wh1b = (float*)alloc((size_t)512 * 512 * 4);
  bf16* Xpf   = (bf16*)alloc((size_t)2048 * 2048 * 2);
  bf16* Xpb   = (bf16*)alloc((size_t)2048 * 2048 * 2);
  bf16* Aff   = (bf16*)alloc((size_t)2048 * 512 * 2);
  bf16* Afb   = (bf16*)alloc((size_t)2048 * 512 * 2);
  bf16* Bmf   = (bf16*)alloc((size_t)2048 * 512 * 2);
  bf16* Bmb   = (bf16*)alloc((size_t)2048 * 512 * 2);
  float* c0f  = (float*)alloc(2048 * 4);
  float* c0b  = (float*)alloc(2048 * 4);
  bf16* st0   = (bf16*)alloc((size_t)32 * 1536 * 2);
  bf16* st1   = (bf16*)alloc((size_t)32 * 1536 * 2);
  float* cst0 = (float*)alloc((size_t)512 * 32 * 4);
  float* cst1 = (float*)alloc((size_t)512 * 32 * 4);

  hipMemsetAsync(d_ws, 0, zero_bytes, stream);

  k_xg<<<4096, 256, 0, stream>>>(emb, trg, xg);
  k_srcb<<<8192, 256, 0, stream>>>(src, srcb);
  k_fcw<<<8192, 256, 0, stream>>>(fcW, fcWb);
  k_wpack<<<2048, 256, 0, stream>>>(fWih, fWhh, bWih, bWhh, fattW, battW, bahW, fahW,
                                    Wxf, Wxb, Wrecf, Wrecb, attWtf, attWtb, ahW2f, ahW2b,
                                    Wh1f, Wh1b);
  k_c0<<<2048, 256, 0, stream>>>(src, fattb, battb, c0f, c0b);
  k_init<<<64, 256, 0, stream>>>(feed, hid, st0, st1, cst0, cst1);

  // Xp[gc][r] = (x @ Wih_x^T)^T  (gc-major so scan reads are b-coalesced)
  gemm_k<bf16, false><<<dim3(16, 16), 256, 0, stream>>>(Wxf, xg, Xpf, nullptr, 2048, 2048, 512);
  gemm_k<bf16, false><<<dim3(16, 16), 256, 0, stream>>>(Wxb, xg, Xpb, nullptr, 2048, 2048, 512);
  // A[r][j] = src @ attW ;  Bm[r][o] = src @ ahW_ct^T
  gemm_k<bf16, false><<<dim3(4, 16), 256, 0, stream>>>(srcb, attWtf, Aff, nullptr, 2048, 512, 1024);
  gemm_k<bf16, false><<<dim3(4, 16), 256, 0, stream>>>(srcb, attWtb, Afb, nullptr, 2048, 512, 1024);
  gemm_k<bf16, false><<<dim3(4, 16), 256, 0, stream>>>(srcb, ahW2f, Bmf, nullptr, 2048, 512, 1024);
  gemm_k<bf16, false><<<dim3(4, 16), 256, 0, stream>>>(srcb, ahW2b, Bmb, nullptr, 2048, 512, 1024);

  ScanP sp;
  sp.Wrec[0] = Wrecf; sp.Wrec[1] = Wrecb;
  sp.Xp[0] = Xpf;     sp.Xp[1] = Xpb;
  sp.Af[0] = Aff;     sp.Af[1] = Afb;
  sp.Bm[0] = Bmf;     sp.Bm[1] = Bmb;
  sp.Wh1[0] = Wh1f;   sp.Wh1[1] = Wh1b;
  sp.bih[0] = fbih;   sp.bih[1] = bbih;
  sp.bhh[0] = fbhh;   sp.bhh[1] = bbhh;
  sp.c0[0] = c0f;     sp.c0[1] = c0b;
  sp.ahb[0] = bahb;   sp.ahb[1] = fahb;   // att_hidden weights are swapped in the reference
  sp.mask = mask;
  sp.st[0] = st0;     sp.st[1] = st1;
  sp.cst[0] = cst0;   sp.cst[1] = cst1;
  sp.hcat = hcat;     sp.bar = bar;
  scan_k<<<64, 256, 0, stream>>>(sp);

  // logits[b*64+t][v] = hcat @ fcW^T + fcb
  gemm_k<float, true><<<dim3(250, 16), 256, 0, stream>>>(hcat, fcWb, (float*)d_out, fcb,
                                                         2048, 32000, 1024);
}

// Round 2
// 4793.450 us; speedup vs baseline: 1.1516x; 1.1516x over previous
//
#include <hip/hip_runtime.h>
#include <hip/hip_bf16.h>
#include <math.h>

typedef __hip_bfloat16 bf16;
typedef __attribute__((ext_vector_type(8))) short short8b;
typedef __attribute__((ext_vector_type(8))) __bf16 bf16x8;
typedef __attribute__((ext_vector_type(4))) float f32x4;

#define SCALE_F 0.04419417382415922f  // 1/sqrt(512)

// ---- MFMA wrapper tolerant of either builtin signature (v8i16 or v8bf16) ----
template <typename V>
static __device__ inline auto mfma_try(V a, V b, f32x4 c, int)
    -> decltype(__builtin_amdgcn_mfma_f32_16x16x32_bf16(a, b, c, 0, 0, 0)) {
  return __builtin_amdgcn_mfma_f32_16x16x32_bf16(a, b, c, 0, 0, 0);
}
template <typename V>
static __device__ inline auto mfma_try(V a, V b, f32x4 c, long)
    -> decltype(__builtin_amdgcn_mfma_f32_16x16x32_bf16(
        __builtin_bit_cast(bf16x8, a), __builtin_bit_cast(bf16x8, b), c, 0, 0, 0)) {
  return __builtin_amdgcn_mfma_f32_16x16x32_bf16(
      __builtin_bit_cast(bf16x8, a), __builtin_bit_cast(bf16x8, b), c, 0, 0, 0);
}
static __device__ inline f32x4 MFMA(short8b a, short8b b, f32x4 c) {
  return mfma_try(a, b, c, 0);
}

static __device__ inline short8b ldb8(const bf16* p) {
  return *reinterpret_cast<const short8b*>(p);
}
static __device__ inline float b2f(bf16 v) { return __bfloat162float(v); }
static __device__ inline bf16 f2b(float v) { return __float2bfloat16(v); }
static __device__ inline float s2f(short s) {
  unsigned u = ((unsigned)(unsigned short)s) << 16;
  return __builtin_bit_cast(float, u);
}
static __device__ inline float sigm(float x) { return 1.f / (1.f + expf(-x)); }

// write-through 2-byte store: bypasses L1/L2, lands at the LLC (device
// coherence point) -> cross-XCD visible without any cache-wide fence ops.
static __device__ inline void st2_wt(bf16* p, float v) {
  unsigned short u = __builtin_bit_cast(unsigned short, f2b(v));
  unsigned ud = u;
  asm volatile("global_store_short %0, %1, off sc0 sc1" ::"v"(p), "v"(ud)
               : "memory");
}

// ---- fence-free device barrier ----
// All cross-block data is written via sc1 write-through stores and read at
// unique (never-before-cached) addresses, so no L2 invalidate/writeback is
// needed: just drain own stores (vmcnt ack == reached LLC), count, spin.
static __device__ inline void gbar(unsigned* cnt, unsigned target) {
  asm volatile("s_waitcnt vmcnt(0)" ::: "memory");
  __syncthreads();
  if (threadIdx.x == 0) {
    __hip_atomic_fetch_add(cnt, 1u, __ATOMIC_RELAXED, __HIP_MEMORY_SCOPE_AGENT);
    while (__hip_atomic_load(cnt, __ATOMIC_RELAXED, __HIP_MEMORY_SCOPE_AGENT) < target) {
      __builtin_amdgcn_s_sleep(2);
    }
  }
  __syncthreads();
}

// =======================  generic MFMA GEMM  =======================
// C[M,N] = A[M,K] @ B[N,K]^T (+bias), A/B bf16 row-major K-contig, fp32 accum.
template <typename OutT, bool HAS_BIAS>
__global__ __launch_bounds__(256) void gemm_k(
    const bf16* __restrict__ A, const bf16* __restrict__ Bw,
    OutT* __restrict__ C, const float* __restrict__ bias,
    int M, int N, int K) {
  const int lane = threadIdx.x & 63;
  const int wid = threadIdx.x >> 6;
  const int m0 = blockIdx.y * 128 + (wid >> 1) * 64;
  const int n0 = blockIdx.x * 128 + (wid & 1) * 64;
  const int lr = lane & 15;
  const int lk = (lane >> 4) * 8;
  f32x4 acc[4][4];
#pragma unroll
  for (int i = 0; i < 4; ++i)
#pragma unroll
    for (int j = 0; j < 4; ++j) acc[i][j] = (f32x4){0.f, 0.f, 0.f, 0.f};
  const bf16* Ap = A + (size_t)(m0 + lr) * K + lk;
  const bf16* Bp = Bw + (size_t)(n0 + lr) * K + lk;
  for (int k0 = 0; k0 < K; k0 += 32) {
    short8b av[4], bv[4];
#pragma unroll
    for (int i = 0; i < 4; ++i) av[i] = ldb8(Ap + (size_t)i * 16 * K + k0);
#pragma unroll
    for (int i = 0; i < 4; ++i) bv[i] = ldb8(Bp + (size_t)i * 16 * K + k0);
#pragma unroll
    for (int mi = 0; mi < 4; ++mi)
#pragma unroll
      for (int ni = 0; ni < 4; ++ni)
        acc[mi][ni] = MFMA(av[mi], bv[ni], acc[mi][ni]);
  }
  const int rb = (lane >> 4) * 4;
#pragma unroll
  for (int mi = 0; mi < 4; ++mi) {
#pragma unroll
    for (int r = 0; r < 4; ++r) {
      const int row = m0 + mi * 16 + rb + r;
#pragma unroll
      for (int ni = 0; ni < 4; ++ni) {
        const int col = n0 + ni * 16 + lr;
        float v = acc[mi][ni][r];
        if (HAS_BIAS) v += bias[col];
        if constexpr (sizeof(OutT) == 2) {
          C[(size_t)row * N + col] = f2b(v);
        } else {
          C[(size_t)row * N + col] = v;
        }
      }
    }
  }
}

// =======================  prep kernels  =======================
__global__ void k_xg(const float* __restrict__ emb, const int* __restrict__ trg,
                     bf16* __restrict__ xg) {
  const int i = blockIdx.x * 256 + threadIdx.x;   // 2048*512 exact
  const int r = i >> 9, e = i & 511;
  const int t = r >> 5, b = r & 31;
  const int tok = trg[b * 64 + t];
  xg[i] = f2b(emb[(size_t)tok * 512 + e]);
}

__global__ void k_srcb(const float* __restrict__ s, bf16* __restrict__ d) {
  const int i = blockIdx.x * 256 + threadIdx.x;   // 2048*1024 exact
  d[i] = f2b(s[i]);
}

__global__ void k_fcw(const float* __restrict__ s, bf16* __restrict__ d) {
  const size_t stride = (size_t)gridDim.x * blockDim.x;
  for (size_t i = blockIdx.x * (size_t)blockDim.x + threadIdx.x;
       i < (size_t)32000 * 1024; i += stride)
    d[i] = f2b(s[i]);
}

__global__ void k_wpack(const float* __restrict__ fWih, const float* __restrict__ fWhh,
                        const float* __restrict__ bWih, const float* __restrict__ bWhh,
                        const float* __restrict__ fattW, const float* __restrict__ battW,
                        const float* __restrict__ bahW, const float* __restrict__ fahW,
                        bf16* Wxf, bf16* Wxb, bf16* Wrecf, bf16* Wrecb,
                        bf16* attWtf, bf16* attWtb, bf16* ahW2f, bf16* ahW2b,
                        float* Wh1f, float* Wh1b) {
  const int stride = gridDim.x * blockDim.x;
  const int i0 = blockIdx.x * blockDim.x + threadIdx.x;
  for (int i = i0; i < 2048 * 512; i += stride) {        // Wih x-slice
    const int gc = i >> 9, k = i & 511;
    Wxf[i] = f2b(fWih[(size_t)gc * 1024 + k]);
    Wxb[i] = f2b(bWih[(size_t)gc * 1024 + k]);
  }
  for (int i = i0; i < 2048 * 1024; i += stride) {       // [Wih_h | Whh]
    const int gc = i >> 10, k = i & 1023;
    float vf, vb;
    if (k < 512) { vf = fWih[(size_t)gc * 1024 + 512 + k]; vb = bWih[(size_t)gc * 1024 + 512 + k]; }
    else         { vf = fWhh[(size_t)gc * 512 + k - 512]; vb = bWhh[(size_t)gc * 512 + k - 512]; }
    Wrecf[i] = f2b(vf); Wrecb[i] = f2b(vb);
  }
  for (int i = i0; i < 512 * 1024; i += stride) {        // attW transpose
    const int j = i >> 10, d = i & 1023;
    attWtf[i] = f2b(fattW[(size_t)d * 512 + j]);
    attWtb[i] = f2b(battW[(size_t)d * 512 + j]);
  }
  for (int i = i0; i < 512 * 1024; i += stride) {        // ah_W ct-slice (swapped: fwd uses bah)
    const int o = i >> 10, d = i & 1023;
    ahW2f[i] = f2b(bahW[(size_t)o * 1536 + 512 + d]);
    ahW2b[i] = f2b(fahW[(size_t)o * 1536 + 512 + d]);
  }
  for (int i = i0; i < 512 * 512; i += stride) {         // ah_W h-slice fp32
    const int o = i >> 9, k = i & 511;
    Wh1f[i] = bahW[(size_t)o * 1536 + k];
    Wh1b[i] = fahW[(size_t)o * 1536 + k];
  }
}

__global__ void k_c0(const float* __restrict__ src, const float* __restrict__ fb,
                     const float* __restrict__ bb, float* __restrict__ c0f,
                     float* __restrict__ c0b) {
  const int r = blockIdx.x;
  const int tid = threadIdx.x;
  float pf = 0.f, pb = 0.f;
  for (int d = tid; d < 1024; d += 256) {
    const float s = src[(size_t)r * 1024 + d];
    pf += s * fb[d];
    pb += s * bb[d];
  }
#pragma unroll
  for (int d = 1; d < 64; d <<= 1) { pf += __shfl_xor(pf, d); pb += __shfl_xor(pb, d); }
  __shared__ float rf[4], rb2[4];
  if ((tid & 63) == 0) { rf[tid >> 6] = pf; rb2[tid >> 6] = pb; }
  __syncthreads();
  if (tid == 0) {
    c0f[r] = (rf[0] + rf[1] + rf[2] + rf[3]) * SCALE_F;
    c0b[r] = (rb2[0] + rb2[1] + rb2[2] + rb2[3]) * SCALE_F;
  }
}

// rolling state buffers per dir: hh[65][32][512], hb[65][32][512] bf16
// (slot t+1 written at step t -> every address written once, read after;
//  readers can cache freely, writers go write-through)
__global__ void k_init(const float* __restrict__ feed, const float* __restrict__ hid,
                       bf16* hh0, bf16* hh1, bf16* hb0, bf16* hb1,
                       float* cst0, float* cst1) {
  const int i = blockIdx.x * 256 + threadIdx.x;   // 32*512 exact
  const int b = i >> 9, k = i & 511;
  hh0[i] = f2b(feed[k]);
  hh1[i] = f2b(feed[512 + k]);
  hb0[i] = f2b(hid[k]);
  hb1[i] = f2b(hid[1024 + k]);
  cst0[k * 32 + b] = hid[512 + k];
  cst1[k * 32 + b] = hid[1536 + k];
}

// =======================  sequential scan  =======================
struct ScanP {
  const bf16* Wrec[2]; const bf16* Xp[2]; const bf16* Af[2]; const bf16* Bm[2];
  const float* Wh1[2]; const float* bih[2]; const float* bhh[2];
  const float* c0[2]; const float* ahb[2]; const float* mask;
  bf16* hh[2]; bf16* hb[2]; float* cst[2]; bf16* hcat; unsigned* bar;
};

__global__ __launch_bounds__(256) void scan_k(ScanP P) {
  const int blk = blockIdx.x;     // 64 blocks
  const int dir = blk >> 5;       // 0 fwd, 1 bwd
  const int g = blk & 31;         // PhaseA: j-slice; PhaseB: batch index
  const int tid = threadIdx.x;
  const int lane = tid & 63;
  const int wv = tid >> 6;

  const bf16* __restrict__ Wrec = P.Wrec[dir];
  const bf16* __restrict__ Xp = P.Xp[dir];
  const bf16* __restrict__ Af = P.Af[dir];
  const bf16* __restrict__ Bm = P.Bm[dir];
  const float* __restrict__ Wh1 = P.Wh1[dir];
  const float* __restrict__ bihp = P.bih[dir];
  const float* __restrict__ bhhp = P.bhh[dir];
  const float* __restrict__ c0v = P.c0[dir];
  const float* __restrict__ ahbp = P.ahb[dir];
  bf16* __restrict__ hhB = P.hh[dir];
  bf16* __restrict__ hbB = P.hb[dir];
  float* __restrict__ cst = P.cst[dir];

  __shared__ float gl[4][16][33];
  __shared__ float h_lds[512];
  __shared__ float w_lds[64];
  __shared__ float p_lds[64];

  unsigned ep = 0;

  for (int t = 0; t < 64; ++t) {
    const bf16* hhR = hhB + (size_t)t * 32 * 512;        // hhat_{t-1}
    bf16* hhW = hhB + (size_t)(t + 1) * 32 * 512;
    const bf16* hbR = hbB + (size_t)t * 32 * 512;        // h_{t-1}
    bf16* hbW = hbB + (size_t)(t + 1) * 32 * 512;

    // ---------- Phase A: gates (MFMA) + LSTM cell, block owns j in [g*16, g*16+16) ----------
    {
      const int gate = wv;                   // wave 0..3 -> i,f,g,o
      const int lr = lane & 15;
      const int kb = lane >> 4;
      const int koff = kb * 8;
      const int gc = gate * 512 + g * 16 + lr;
      const bf16* Brow = Wrec + (size_t)gc * 1024;
      const bf16* A0h = hhR + (size_t)lr * 512;
      const bf16* A1h = hhR + (size_t)(lr + 16) * 512;
      const bf16* A0g = hbR + (size_t)lr * 512;
      const bf16* A1g = hbR + (size_t)(lr + 16) * 512;
      f32x4 ac0 = (f32x4){0.f, 0.f, 0.f, 0.f};
      f32x4 ac1 = (f32x4){0.f, 0.f, 0.f, 0.f};
#pragma unroll
      for (int ks = 0; ks < 16; ++ks) {      // hhat part (k 0..511)
        const int k = ks * 32 + koff;
        const short8b bv = ldb8(Brow + k);
        ac0 = MFMA(ldb8(A0h + k), bv, ac0);
        ac1 = MFMA(ldb8(A1h + k), bv, ac1);
      }
#pragma unroll
      for (int ks = 0; ks < 16; ++ks) {      // h part (k 512..1023)
        const int k = ks * 32 + koff;
        const short8b bv = ldb8(Brow + 512 + k);
        ac0 = MFMA(ldb8(A0g + k), bv, ac0);
        ac1 = MFMA(ldb8(A1g + k), bv, ac1);
      }
      const int tcol = dir ? (63 - t) : t;
      const float bsum = bihp[gc] + bhhp[gc];
      const bf16* xpc = Xp + (size_t)gc * 2048 + tcol * 32;
#pragma unroll
      for (int r = 0; r < 4; ++r) {
        const int brow = kb * 4 + r;         // D: row=(lane>>4)*4+reg, col=lane&15
        gl[gate][lr][brow] = ac0[r] + b2f(xpc[brow]) + bsum;
        gl[gate][lr][brow + 16] = ac1[r] + b2f(xpc[brow + 16]) + bsum;
      }
    }
    __syncthreads();
    {
      const int b = tid & 31;
#pragma unroll
      for (int it = 0; it < 2; ++it) {
        const int jl = (tid >> 5) + it * 8;
        const int j = g * 16 + jl;
        const float gi = gl[0][jl][b];
        const float gf = gl[1][jl][b];
        const float gg = gl[2][jl][b];
        const float go = gl[3][jl][b];
        float cn = sigm(gf) * cst[j * 32 + b] + sigm(gi) * tanhf(gg);
        float hn = sigm(go) * tanhf(cn);
        if (dir) {
          const float m = P.mask[b * 64 + (63 - t)];
          hn *= m; cn *= m;
        }
        cst[j * 32 + b] = cn;                               // block-private
        st2_wt(hbW + (size_t)b * 512 + j, hn);              // write-through
      }
    }
    ++ep; gbar(P.bar, ep * 64u);

    // ---------- Phase B: attention + hhat for batch b = g ----------
    {
      const bf16* hrow = hbW + (size_t)g * 512;   // fresh unique address
      if (tid < 64) {
        const short8b v = ldb8(hrow + tid * 8);
#pragma unroll
        for (int e = 0; e < 8; ++e) h_lds[tid * 8 + e] = s2f(v[e]);
      }
    }
    __syncthreads();
    {
      const int s = tid >> 2, q = tid & 3;
      const bf16* arow = Af + (size_t)(g * 64 + s) * 512 + q * 128;
      float part = 0.f;
#pragma unroll 4
      for (int k8 = 0; k8 < 128; k8 += 8) {
        const short8b v = ldb8(arow + k8);
#pragma unroll
        for (int e = 0; e < 8; ++e) part += h_lds[q * 128 + k8 + e] * s2f(v[e]);
      }
      part += __shfl_xor(part, 1);
      part += __shfl_xor(part, 2);
      if (q == 0) w_lds[s] = part * SCALE_F + c0v[g * 64 + s];
    }
    __syncthreads();
    if (tid < 64) {
      const float v = w_lds[tid];
      float mx = v;
#pragma unroll
      for (int d = 1; d < 64; d <<= 1) mx = fmaxf(mx, __shfl_xor(mx, d));
      const float e = expf(v - mx);
      float sm = e;
#pragma unroll
      for (int d = 1; d < 64; d <<= 1) sm += __shfl_xor(sm, d);
      p_lds[tid] = e / sm;
    }
    __syncthreads();
    {
#pragma unroll
      for (int it = 0; it < 2; ++it) {
        const int o = tid + it * 256;
        float acc = ahbp[o];
        const float* wrow = Wh1 + (size_t)o * 512;
#pragma unroll 2
        for (int k = 0; k < 512; k += 4) {
          const float4 w4 = *reinterpret_cast<const float4*>(wrow + k);
          acc += h_lds[k] * w4.x + h_lds[k + 1] * w4.y + h_lds[k + 2] * w4.z + h_lds[k + 3] * w4.w;
        }
        const bf16* bmc = Bm + (size_t)(g * 64) * 512 + o;
        float acc2 = 0.f;
#pragma unroll 4
        for (int s2 = 0; s2 < 64; ++s2) acc2 += p_lds[s2] * b2f(bmc[(size_t)s2 * 512]);
        const float hh = tanhf(acc + acc2);
        st2_wt(hhW + (size_t)g * 512 + o, hh);                                // write-through
        if (dir == 0) {
          P.hcat[(size_t)(g * 64 + t) * 1024 + o] = f2b(hh);                  // f_out[:, t]
        } else if (t >= 2) {
          P.hcat[(size_t)(g * 64 + t - 2) * 1024 + 512 + o] = f2b(hh);        // b_shift
        }
      }
    }
    ++ep; gbar(P.bar, ep * 64u);
  }
}

// =======================  host  =======================
extern "C" void kernel_launch(void* const* d_in, const int* in_sizes, int n_in,
                              void* d_out, int out_size, void* d_ws, size_t ws_size,
                              hipStream_t stream) {
  (void)in_sizes; (void)n_in; (void)out_size; (void)ws_size;
  const float* src  = (const float*)d_in[0];
  const int*   trg  = (const int*)d_in[1];
  const float* mask = (const float*)d_in[2];
  const float* emb  = (const float*)d_in[3];
  const float* fWih = (const float*)d_in[4];
  const float* fWhh = (const float*)d_in[5];
  const float* fbih = (const float*)d_in[6];
  const float* fbhh = (const float*)d_in[7];
  const float* bWih = (const float*)d_in[8];
  const float* bWhh = (const float*)d_in[9];
  const float* bbih = (const float*)d_in[10];
  const float* bbhh = (const float*)d_in[11];
  const float* fattW = (const float*)d_in[12];
  const float* fattb = (const float*)d_in[13];
  const float* battW = (const float*)d_in[14];
  const float* battb = (const float*)d_in[15];
  const float* fahW = (const float*)d_in[16];
  const float* fahb = (const float*)d_in[17];
  const float* bahW = (const float*)d_in[18];
  const float* bahb = (const float*)d_in[19];
  const float* fcW  = (const float*)d_in[20];
  const float* fcb  = (const float*)d_in[21];
  const float* feed = (const float*)d_in[22];
  const float* hid  = (const float*)d_in[23];

  char* wsp = (char*)d_ws;
  size_t off = 0;
  auto alloc = [&](size_t bytes) -> void* {
    void* p = wsp + off;
    off += (bytes + 255) & ~(size_t)255;
    return p;
  };
  unsigned* bar = (unsigned*)alloc(256);
  bf16* hcat = (bf16*)alloc((size_t)2048 * 1024 * 2);
  const size_t zero_bytes = off;                 // bar + hcat zeroed per launch
  bf16* xg    = (bf16*)alloc((size_t)2048 * 512 * 2);
  bf16* srcb  = (bf16*)alloc((size_t)2048 * 1024 * 2);
  bf16* fcWb  = (bf16*)alloc((size_t)32000 * 1024 * 2);
  bf16* Wxf   = (bf16*)alloc((size_t)2048 * 512 * 2);
  bf16* Wxb   = (bf16*)alloc((size_t)2048 * 512 * 2);
  bf16* Wrecf = (bf16*)alloc((size_t)2048 * 1024 * 2);
  bf16* Wrecb = (bf16*)alloc((size_t)2048 * 1024 * 2);
  bf16* attWtf = (bf16*)alloc((size_t)512 * 1024 * 2);
  bf16* attWtb = (bf16*)alloc((size_t)512 * 1024 * 2);
  bf16* ahW2f = (bf16*)alloc((size_t)512 * 1024 * 2);
  bf16* ahW2b = (bf16*)alloc((size_t)512 * 1024 * 2);
  float* Wh1f = (float*)alloc((size_t)512 * 512 * 4);
  float* Wh1b = (float*)alloc((size_t)512 * 512 * 4);
  bf16* Xpf   = (bf16*)alloc((size_t)2048 * 2048 * 2);
  bf16* Xpb   = (bf16*)alloc((size_t)2048 * 2048 * 2);
  bf16* Aff   = (bf16*)alloc((size_t)2048 * 512 * 2);
  bf16* Afb   = (bf16*)alloc((size_t)2048 * 512 * 2);
  bf16* Bmf   = (bf16*)alloc((size_t)2048 * 512 * 2);
  bf16* Bmb   = (bf16*)alloc((size_t)2048 * 512 * 2);
  float* c0f  = (float*)alloc(2048 * 4);
  float* c0b  = (float*)alloc(2048 * 4);
  bf16* hh0   = (bf16*)alloc((size_t)65 * 32 * 512 * 2);
  bf16* hh1   = (bf16*)alloc((size_t)65 * 32 * 512 * 2);
  bf16* hb0   = (bf16*)alloc((size_t)65 * 32 * 512 * 2);
  bf16* hb1   = (bf16*)alloc((size_t)65 * 32 * 512 * 2);
  float* cst0 = (float*)alloc((size_t)512 * 32 * 4);
  float* cst1 = (float*)alloc((size_t)512 * 32 * 4);

  hipMemsetAsync(d_ws, 0, zero_bytes, stream);

  k_xg<<<4096, 256, 0, stream>>>(emb, trg, xg);
  k_srcb<<<8192, 256, 0, stream>>>(src, srcb);
  k_fcw<<<8192, 256, 0, stream>>>(fcW, fcWb);
  k_wpack<<<2048, 256, 0, stream>>>(fWih, fWhh, bWih, bWhh, fattW, battW, bahW, fahW,
                                    Wxf, Wxb, Wrecf, Wrecb, attWtf, attWtb, ahW2f, ahW2b,
                                    Wh1f, Wh1b);
  k_c0<<<2048, 256, 0, stream>>>(src, fattb, battb, c0f, c0b);
  k_init<<<64, 256, 0, stream>>>(feed, hid, hh0, hh1, hb0, hb1, cst0, cst1);

  // Xp[gc][r] = (x @ Wih_x^T)^T  (gc-major so scan reads are b-coalesced)
  gemm_k<bf16, false><<<dim3(16, 16), 256, 0, stream>>>(Wxf, xg, Xpf, nullptr, 2048, 2048, 512);
  gemm_k<bf16, false><<<dim3(16, 16), 256, 0, stream>>>(Wxb, xg, Xpb, nullptr, 2048, 2048, 512);
  // A[r][j] = src @ attW ;  Bm[r][o] = src @ ahW_ct^T
  gemm_k<bf16, false><<<dim3(4, 16), 256, 0, stream>>>(srcb, attWtf, Aff, nullptr, 2048, 512, 1024);
  gemm_k<bf16, false><<<dim3(4, 16), 256, 0, stream>>>(srcb, attWtb, Afb, nullptr, 2048, 512, 1024);
  gemm_k<bf16, false><<<dim3(4, 16), 256, 0, stream>>>(srcb, ahW2f, Bmf, nullptr, 2048, 512, 1024);
  gemm_k<bf16, false><<<dim3(4, 16), 256, 0, stream>>>(srcb, ahW2b, Bmb, nullptr, 2048, 512, 1024);

  ScanP sp;
  sp.Wrec[0] = Wrecf; sp.Wrec[1] = Wrecb;
  sp.Xp[0] = Xpf;     sp.Xp[1] = Xpb;
  sp.Af[0] = Aff;     sp.Af[1] = Afb;
  sp.Bm[0] = Bmf;     sp.Bm[1] = Bmb;
  sp.Wh1[0] = Wh1f;   sp.Wh1[1] = Wh1b;
  sp.bih[0] = fbih;   sp.bih[1] = bbih;
  sp.bhh[0] = fbhh;   sp.bhh[1] = bbhh;
  sp.c0[0] = c0f;     sp.c0[1] = c0b;
  sp.ahb[0] = bahb;   sp.ahb[1] = fahb;   // att_hidden weights are swapped in the reference
  sp.mask = mask;
  sp.hh[0] = hh0;     sp.hh[1] = hh1;
  sp.hb[0] = hb0;     sp.hb[1] = hb1;
  sp.cst[0] = cst0;   sp.cst[1] = cst1;
  sp.hcat = hcat;     sp.bar = bar;
  scan_k<<<64, 256, 0, stream>>>(sp);

  // logits[b*64+t][v] = hcat @ fcW^T + fcb
  gemm_k<float, true><<<dim3(250, 16), 256, 0, stream>>>(hcat, fcWb, (float*)d_out, fcb,
                                                         2048, 32000, 1024);
}

// Round 3
// 2920.215 us; speedup vs baseline: 1.8903x; 1.6415x over previous
//
#include <hip/hip_runtime.h>
#include <hip/hip_bf16.h>
#include <math.h>

typedef __hip_bfloat16 bf16;
typedef __attribute__((ext_vector_type(8))) short short8b;
typedef __attribute__((ext_vector_type(8))) __bf16 bf16x8;
typedef __attribute__((ext_vector_type(4))) float f32x4;

#define SCALE_F 0.04419417382415922f  // 1/sqrt(512)

// ---- MFMA wrapper tolerant of either builtin signature (v8i16 or v8bf16) ----
template <typename V>
static __device__ inline auto mfma_try(V a, V b, f32x4 c, int)
    -> decltype(__builtin_amdgcn_mfma_f32_16x16x32_bf16(a, b, c, 0, 0, 0)) {
  return __builtin_amdgcn_mfma_f32_16x16x32_bf16(a, b, c, 0, 0, 0);
}
template <typename V>
static __device__ inline auto mfma_try(V a, V b, f32x4 c, long)
    -> decltype(__builtin_amdgcn_mfma_f32_16x16x32_bf16(
        __builtin_bit_cast(bf16x8, a), __builtin_bit_cast(bf16x8, b), c, 0, 0, 0)) {
  return __builtin_amdgcn_mfma_f32_16x16x32_bf16(
      __builtin_bit_cast(bf16x8, a), __builtin_bit_cast(bf16x8, b), c, 0, 0, 0);
}
static __device__ inline f32x4 MFMA(short8b a, short8b b, f32x4 c) {
  return mfma_try(a, b, c, 0);
}

static __device__ inline short8b ldb8(const bf16* p) {
  return *reinterpret_cast<const short8b*>(p);
}
static __device__ inline float b2f(bf16 v) { return __bfloat162float(v); }
static __device__ inline bf16 f2b(float v) { return __float2bfloat16(v); }
static __device__ inline float s2f(short s) {
  unsigned u = ((unsigned)(unsigned short)s) << 16;
  return __builtin_bit_cast(float, u);
}
static __device__ inline float sigm(float x) { return 1.f / (1.f + expf(-x)); }

// write-through 2-byte store: bypasses L1/L2, lands at the LLC (device
// coherence point) -> cross-XCD visible without any cache-wide fence ops.
static __device__ inline void st2_wt(bf16* p, float v) {
  unsigned short u = __builtin_bit_cast(unsigned short, f2b(v));
  unsigned ud = u;
  asm volatile("global_store_short %0, %1, off sc0 sc1" ::"v"(p), "v"(ud)
               : "memory");
}

// ---- fence-free device barrier ----
// Cross-block data goes through sc1 write-through stores and is read at
// per-step-unique (never-before-cached) addresses, so no cache maintenance
// is needed: drain own stores (vmcnt ack == reached LLC), count, spin.
static __device__ inline void gbar(unsigned* cnt, unsigned target) {
  asm volatile("s_waitcnt vmcnt(0)" ::: "memory");
  __syncthreads();
  if (threadIdx.x == 0) {
    __hip_atomic_fetch_add(cnt, 1u, __ATOMIC_RELAXED, __HIP_MEMORY_SCOPE_AGENT);
    while (__hip_atomic_load(cnt, __ATOMIC_RELAXED, __HIP_MEMORY_SCOPE_AGENT) < target) {
      __builtin_amdgcn_s_sleep(2);
    }
  }
  __syncthreads();
}

// =======================  generic MFMA GEMM  =======================
// C[M,N] = A[M,K] @ B[N,K]^T (+bias), A/B bf16 row-major K-contig, fp32 accum.
template <typename OutT, bool HAS_BIAS>
__global__ __launch_bounds__(256) void gemm_k(
    const bf16* __restrict__ A, const bf16* __restrict__ Bw,
    OutT* __restrict__ C, const float* __restrict__ bias,
    int M, int N, int K) {
  const int lane = threadIdx.x & 63;
  const int wid = threadIdx.x >> 6;
  const int m0 = blockIdx.y * 128 + (wid >> 1) * 64;
  const int n0 = blockIdx.x * 128 + (wid & 1) * 64;
  const int lr = lane & 15;
  const int lk = (lane >> 4) * 8;
  f32x4 acc[4][4];
#pragma unroll
  for (int i = 0; i < 4; ++i)
#pragma unroll
    for (int j = 0; j < 4; ++j) acc[i][j] = (f32x4){0.f, 0.f, 0.f, 0.f};
  const bf16* Ap = A + (size_t)(m0 + lr) * K + lk;
  const bf16* Bp = Bw + (size_t)(n0 + lr) * K + lk;
  for (int k0 = 0; k0 < K; k0 += 32) {
    short8b av[4], bv[4];
#pragma unroll
    for (int i = 0; i < 4; ++i) av[i] = ldb8(Ap + (size_t)i * 16 * K + k0);
#pragma unroll
    for (int i = 0; i < 4; ++i) bv[i] = ldb8(Bp + (size_t)i * 16 * K + k0);
#pragma unroll
    for (int mi = 0; mi < 4; ++mi)
#pragma unroll
      for (int ni = 0; ni < 4; ++ni)
        acc[mi][ni] = MFMA(av[mi], bv[ni], acc[mi][ni]);
  }
  const int rb = (lane >> 4) * 4;
#pragma unroll
  for (int mi = 0; mi < 4; ++mi) {
#pragma unroll
    for (int r = 0; r < 4; ++r) {
      const int row = m0 + mi * 16 + rb + r;
#pragma unroll
      for (int ni = 0; ni < 4; ++ni) {
        const int col = n0 + ni * 16 + lr;
        float v = acc[mi][ni][r];
        if (HAS_BIAS) v += bias[col];
        if constexpr (sizeof(OutT) == 2) {
          C[(size_t)row * N + col] = f2b(v);
        } else {
          C[(size_t)row * N + col] = v;
        }
      }
    }
  }
}

// =======================  prep kernels  =======================
__global__ void k_xg(const float* __restrict__ emb, const int* __restrict__ trg,
                     bf16* __restrict__ xg) {
  const int i = blockIdx.x * 256 + threadIdx.x;   // 2048*512 exact
  const int r = i >> 9, e = i & 511;
  const int t = r >> 5, b = r & 31;
  const int tok = trg[b * 64 + t];
  xg[i] = f2b(emb[(size_t)tok * 512 + e]);
}

__global__ void k_srcb(const float* __restrict__ s, bf16* __restrict__ d) {
  const int i = blockIdx.x * 256 + threadIdx.x;   // 2048*1024 exact
  d[i] = f2b(s[i]);
}

__global__ void k_fcw(const float* __restrict__ s, bf16* __restrict__ d) {
  const size_t stride = (size_t)gridDim.x * blockDim.x;
  for (size_t i = blockIdx.x * (size_t)blockDim.x + threadIdx.x;
       i < (size_t)32000 * 1024; i += stride)
    d[i] = f2b(s[i]);
}

__global__ void k_wpack(const float* __restrict__ fWih, const float* __restrict__ fWhh,
                        const float* __restrict__ bWih, const float* __restrict__ bWhh,
                        const float* __restrict__ fattW, const float* __restrict__ battW,
                        const float* __restrict__ bahW, const float* __restrict__ fahW,
                        bf16* Wxf, bf16* Wxb, bf16* Wrecf, bf16* Wrecb,
                        bf16* attWtf, bf16* attWtb, bf16* ahW2f, bf16* ahW2b,
                        bf16* Wh1f, bf16* Wh1b) {
  const int stride = gridDim.x * blockDim.x;
  const int i0 = blockIdx.x * blockDim.x + threadIdx.x;
  for (int i = i0; i < 2048 * 512; i += stride) {        // Wih x-slice
    const int gc = i >> 9, k = i & 511;
    Wxf[i] = f2b(fWih[(size_t)gc * 1024 + k]);
    Wxb[i] = f2b(bWih[(size_t)gc * 1024 + k]);
  }
  for (int i = i0; i < 2048 * 1024; i += stride) {       // [Wih_h | Whh]
    const int gc = i >> 10, k = i & 1023;
    float vf, vb;
    if (k < 512) { vf = fWih[(size_t)gc * 1024 + 512 + k]; vb = bWih[(size_t)gc * 1024 + 512 + k]; }
    else         { vf = fWhh[(size_t)gc * 512 + k - 512]; vb = bWhh[(size_t)gc * 512 + k - 512]; }
    Wrecf[i] = f2b(vf); Wrecb[i] = f2b(vb);
  }
  for (int i = i0; i < 512 * 1024; i += stride) {        // attW transpose
    const int j = i >> 10, d = i & 1023;
    attWtf[i] = f2b(fattW[(size_t)d * 512 + j]);
    attWtb[i] = f2b(battW[(size_t)d * 512 + j]);
  }
  for (int i = i0; i < 512 * 1024; i += stride) {        // ah_W ct-slice (swapped: fwd uses bah)
    const int o = i >> 10, d = i & 1023;
    ahW2f[i] = f2b(bahW[(size_t)o * 1536 + 512 + d]);
    ahW2b[i] = f2b(fahW[(size_t)o * 1536 + 512 + d]);
  }
  for (int i = i0; i < 512 * 512; i += stride) {         // ah_W h-slice bf16 [o][k]
    const int o = i >> 9, k = i & 511;
    Wh1f[i] = f2b(bahW[(size_t)o * 1536 + k]);
    Wh1b[i] = f2b(fahW[(size_t)o * 1536 + k]);
  }
}

__global__ void k_c0(const float* __restrict__ src, const float* __restrict__ fb,
                     const float* __restrict__ bb, float* __restrict__ c0f,
                     float* __restrict__ c0b) {
  const int r = blockIdx.x;
  const int tid = threadIdx.x;
  float pf = 0.f, pb = 0.f;
  for (int d = tid; d < 1024; d += 256) {
    const float s = src[(size_t)r * 1024 + d];
    pf += s * fb[d];
    pb += s * bb[d];
  }
#pragma unroll
  for (int d = 1; d < 64; d <<= 1) { pf += __shfl_xor(pf, d); pb += __shfl_xor(pb, d); }
  __shared__ float rf[4], rb2[4];
  if ((tid & 63) == 0) { rf[tid >> 6] = pf; rb2[tid >> 6] = pb; }
  __syncthreads();
  if (tid == 0) {
    c0f[r] = (rf[0] + rf[1] + rf[2] + rf[3]) * SCALE_F;
    c0b[r] = (rb2[0] + rb2[1] + rb2[2] + rb2[3]) * SCALE_F;
  }
}

// rolling state buffers per dir: hh[65][32][512], hb[65][32][512] bf16
__global__ void k_init(const float* __restrict__ feed, const float* __restrict__ hid,
                       bf16* hh0, bf16* hh1, bf16* hb0, bf16* hb1,
                       float* cst0, float* cst1) {
  const int i = blockIdx.x * 256 + threadIdx.x;   // 32*512 exact
  const int b = i >> 9, k = i & 511;
  hh0[i] = f2b(feed[k]);
  hh1[i] = f2b(feed[512 + k]);
  hb0[i] = f2b(hid[k]);
  hb1[i] = f2b(hid[1024 + k]);
  cst0[k * 32 + b] = hid[512 + k];
  cst1[k * 32 + b] = hid[1536 + k];
}

// =======================  sequential scan  =======================
struct ScanP {
  const bf16* Wrec[2]; const bf16* Xp[2]; const bf16* Af[2]; const bf16* Bm[2];
  const bf16* Wh1[2]; const float* bih[2]; const float* bhh[2];
  const float* c0[2]; const float* ahb[2]; const float* mask;
  bf16* hh[2]; bf16* hb[2]; bf16* U[2]; float* cst[2]; bf16* hcat; unsigned* bar;
};

__global__ __launch_bounds__(256) void scan_k(ScanP P) {
  const int blk = blockIdx.x;     // 64 blocks
  const int dir = blk >> 5;       // 0 fwd, 1 bwd
  const int g = blk & 31;         // PhaseA/B1: j-slice; PhaseB2/C: batch index
  const int tid = threadIdx.x;
  const int lane = tid & 63;
  const int wv = tid >> 6;

  const bf16* __restrict__ Wrec = P.Wrec[dir];
  const bf16* __restrict__ Xp = P.Xp[dir];
  const bf16* __restrict__ Af = P.Af[dir];
  const bf16* __restrict__ Bm = P.Bm[dir];
  const bf16* __restrict__ Wh1 = P.Wh1[dir];
  const float* __restrict__ bihp = P.bih[dir];
  const float* __restrict__ bhhp = P.bhh[dir];
  const float* __restrict__ c0v = P.c0[dir];
  const float* __restrict__ ahbp = P.ahb[dir];
  bf16* __restrict__ hhB = P.hh[dir];
  bf16* __restrict__ hbB = P.hb[dir];
  bf16* __restrict__ Ubuf = P.U[dir];
  float* __restrict__ cst = P.cst[dir];

  __shared__ float gl[4][16][33];
  __shared__ float h_lds[512];
  __shared__ float w_part[2][64];
  __shared__ float p_lds[64];

  unsigned ep = 0;
  const int lr16 = lane & 15;
  const int koff = (lane >> 4) * 8;

  // prefetched h_{t-1} A-fragments (rows lr16, lr16+16), registers
  short8b pA0[16], pA1[16];
  {
    const bf16* A0 = hbB + (size_t)lr16 * 512;           // slot 0 = h_{-1}
    const bf16* A1 = hbB + (size_t)(lr16 + 16) * 512;
#pragma unroll
    for (int ks = 0; ks < 16; ++ks) {
      pA0[ks] = ldb8(A0 + ks * 32 + koff);
      pA1[ks] = ldb8(A1 + ks * 32 + koff);
    }
  }

  for (int t = 0; t < 64; ++t) {
    const bf16* hhR = hhB + (size_t)t * 32 * 512;        // hhat_{t-1}
    bf16* hhW = hhB + (size_t)(t + 1) * 32 * 512;
    bf16* hbW = hbB + (size_t)(t + 1) * 32 * 512;        // h_t (written below)

    // ---------- Phase A: gates (MFMA) + LSTM cell, block owns j-slice ----------
    {
      const int gate = wv;                   // wave 0..3 -> i,f,g,o
      const int gc = gate * 512 + g * 16 + lr16;
      const bf16* Brow = Wrec + (size_t)gc * 1024;
      const bf16* A0h = hhR + (size_t)lr16 * 512;
      const bf16* A1h = hhR + (size_t)(lr16 + 16) * 512;
      f32x4 ac0 = (f32x4){0.f, 0.f, 0.f, 0.f};
      f32x4 ac1 = (f32x4){0.f, 0.f, 0.f, 0.f};
#pragma unroll
      for (int ks = 0; ks < 16; ++ks) {      // h part first (prefetched regs)
        const int k = ks * 32 + koff;
        const short8b bv = ldb8(Brow + 512 + k);
        ac0 = MFMA(pA0[ks], bv, ac0);
        ac1 = MFMA(pA1[ks], bv, ac1);
      }
#pragma unroll
      for (int ks = 0; ks < 16; ++ks) {      // hhat part (fresh loads)
        const int k = ks * 32 + koff;
        const short8b bv = ldb8(Brow + k);
        ac0 = MFMA(ldb8(A0h + k), bv, ac0);
        ac1 = MFMA(ldb8(A1h + k), bv, ac1);
      }
      const int tcol = dir ? (63 - t) : t;
      const float bsum = bihp[gc] + bhhp[gc];
      const bf16* xpc = Xp + (size_t)gc * 2048 + tcol * 32;
#pragma unroll
      for (int r = 0; r < 4; ++r) {
        const int brow = (lane >> 4) * 4 + r; // D: row=(lane>>4)*4+reg (batch), col=lane&15 (gc)
        gl[gate][lr16][brow] = ac0[r] + b2f(xpc[brow]) + bsum;
        gl[gate][lr16][brow + 16] = ac1[r] + b2f(xpc[brow + 16]) + bsum;
      }
    }
    __syncthreads();
    {
      const int b = tid & 31;
#pragma unroll
      for (int it = 0; it < 2; ++it) {
        const int jl = (tid >> 5) + it * 8;
        const int j = g * 16 + jl;
        const float gi = gl[0][jl][b];
        const float gf = gl[1][jl][b];
        const float gg = gl[2][jl][b];
        const float go = gl[3][jl][b];
        float cn = sigm(gf) * cst[j * 32 + b] + sigm(gi) * tanhf(gg);
        float hn = sigm(go) * tanhf(cn);
        if (dir) {
          const float m = P.mask[b * 64 + (63 - t)];
          hn *= m; cn *= m;
        }
        cst[j * 32 + b] = cn;                               // block-private
        st2_wt(hbW + (size_t)b * 512 + j, hn);              // write-through
      }
    }
    ++ep; gbar(P.bar, ep * 64u);

    // ---------- Phase B: U (wave 0, j-slice) + attention (waves 1-3, batch g) ----------
    if (wv == 0) {
      // U[b, o-slice] = Wh1[o-slice,:] . h_t[b,:]   (MFMA, K=512)
      const bf16* Brow = Wh1 + (size_t)(g * 16 + lr16) * 512;
      const bf16* A0 = hbW + (size_t)lr16 * 512;
      const bf16* A1 = hbW + (size_t)(lr16 + 16) * 512;
      f32x4 u0 = (f32x4){0.f, 0.f, 0.f, 0.f};
      f32x4 u1 = (f32x4){0.f, 0.f, 0.f, 0.f};
#pragma unroll
      for (int ks = 0; ks < 16; ++ks) {
        const int k = ks * 32 + koff;
        const short8b bv = ldb8(Brow + k);
        u0 = MFMA(ldb8(A0 + k), bv, u0);
        u1 = MFMA(ldb8(A1 + k), bv, u1);
      }
      bf16* Uw = Ubuf + (size_t)t * 32 * 512;
      const int o = g * 16 + lr16;
#pragma unroll
      for (int r = 0; r < 4; ++r) {
        const int b0 = (lane >> 4) * 4 + r;
        st2_wt(Uw + (size_t)b0 * 512 + o, u0[r]);
        st2_wt(Uw + (size_t)(b0 + 16) * 512 + o, u1[r]);
      }
    } else if (wv == 1) {
      const short8b v = ldb8(hbW + (size_t)g * 512 + lane * 8);  // h_t[g,:] -> LDS
#pragma unroll
      for (int e = 0; e < 8; ++e) h_lds[lane * 8 + e] = s2f(v[e]);
    }
    __syncthreads();
    if (wv == 1 || wv == 2) {
      const int s = lane, q = wv - 1;
      const bf16* arow = Af + (size_t)(g * 64 + s) * 512 + q * 256;
      float part = 0.f;
#pragma unroll 4
      for (int k8 = 0; k8 < 256; k8 += 8) {
        const short8b v = ldb8(arow + k8);
#pragma unroll
        for (int e = 0; e < 8; ++e) part += h_lds[q * 256 + k8 + e] * s2f(v[e]);
      }
      w_part[q][s] = part;
    }
    __syncthreads();
    if (wv == 3) {
      const float v = (w_part[0][lane] + w_part[1][lane]) * SCALE_F + c0v[g * 64 + lane];
      float mx = v;
#pragma unroll
      for (int d = 1; d < 64; d <<= 1) mx = fmaxf(mx, __shfl_xor(mx, d));
      const float e = expf(v - mx);
      float sm = e;
#pragma unroll
      for (int d = 1; d < 64; d <<= 1) sm += __shfl_xor(sm, d);
      p_lds[lane] = e / sm;
    }
    __syncthreads();
    float a2[2];
#pragma unroll
    for (int it = 0; it < 2; ++it) {           // acc2 = ahb + p . Bm   (all 256 thr)
      const int o = tid + it * 256;
      float acc = ahbp[o];
      const bf16* bmc = Bm + (size_t)(g * 64) * 512 + o;
#pragma unroll 4
      for (int s2 = 0; s2 < 64; ++s2) acc += p_lds[s2] * b2f(bmc[(size_t)s2 * 512]);
      a2[it] = acc;
    }
    ++ep; gbar(P.bar, ep * 64u);

    // ---------- Phase C: hhat = tanh(U + acc2), batch g ----------
    {
      const bf16* Ur = Ubuf + ((size_t)t * 32 + g) * 512;
#pragma unroll
      for (int it = 0; it < 2; ++it) {
        const int o = tid + it * 256;
        const float hh = tanhf(a2[it] + b2f(Ur[o]));
        st2_wt(hhW + (size_t)g * 512 + o, hh);                              // write-through
        if (dir == 0) {
          P.hcat[(size_t)(g * 64 + t) * 1024 + o] = f2b(hh);                // f_out[:, t]
        } else if (t >= 2) {
          P.hcat[(size_t)(g * 64 + t - 2) * 1024 + 512 + o] = f2b(hh);      // b_shift
        }
      }
      if (t < 63) {                            // prefetch h_t frags for next Phase A
        const bf16* A0 = hbW + (size_t)lr16 * 512;
        const bf16* A1 = hbW + (size_t)(lr16 + 16) * 512;
#pragma unroll
        for (int ks = 0; ks < 16; ++ks) {
          pA0[ks] = ldb8(A0 + ks * 32 + koff);
          pA1[ks] = ldb8(A1 + ks * 32 + koff);
        }
      }
    }
    ++ep; gbar(P.bar, ep * 64u);
  }
}

// =======================  host  =======================
extern "C" void kernel_launch(void* const* d_in, const int* in_sizes, int n_in,
                              void* d_out, int out_size, void* d_ws, size_t ws_size,
                              hipStream_t stream) {
  (void)in_sizes; (void)n_in; (void)out_size; (void)ws_size;
  const float* src  = (const float*)d_in[0];
  const int*   trg  = (const int*)d_in[1];
  const float* mask = (const float*)d_in[2];
  const float* emb  = (const float*)d_in[3];
  const float* fWih = (const float*)d_in[4];
  const float* fWhh = (const float*)d_in[5];
  const float* fbih = (const float*)d_in[6];
  const float* fbhh = (const float*)d_in[7];
  const float* bWih = (const float*)d_in[8];
  const float* bWhh = (const float*)d_in[9];
  const float* bbih = (const float*)d_in[10];
  const float* bbhh = (const float*)d_in[11];
  const float* fattW = (const float*)d_in[12];
  const float* fattb = (const float*)d_in[13];
  const float* battW = (const float*)d_in[14];
  const float* battb = (const float*)d_in[15];
  const float* fahW = (const float*)d_in[16];
  const float* fahb = (const float*)d_in[17];
  const float* bahW = (const float*)d_in[18];
  const float* bahb = (const float*)d_in[19];
  const float* fcW  = (const float*)d_in[20];
  const float* fcb  = (const float*)d_in[21];
  const float* feed = (const float*)d_in[22];
  const float* hid  = (const float*)d_in[23];

  char* wsp = (char*)d_ws;
  size_t off = 0;
  auto alloc = [&](size_t bytes) -> void* {
    void* p = wsp + off;
    off += (bytes + 255) & ~(size_t)255;
    return p;
  };
  unsigned* bar = (unsigned*)alloc(256);
  bf16* hcat = (bf16*)alloc((size_t)2048 * 1024 * 2);
  const size_t zero_bytes = off;                 // bar + hcat zeroed per launch
  bf16* xg    = (bf16*)alloc((size_t)2048 * 512 * 2);
  bf16* srcb  = (bf16*)alloc((size_t)2048 * 1024 * 2);
  bf16* fcWb  = (bf16*)alloc((size_t)32000 * 1024 * 2);
  bf16* Wxf   = (bf16*)alloc((size_t)2048 * 512 * 2);
  bf16* Wxb   = (bf16*)alloc((size_t)2048 * 512 * 2);
  bf16* Wrecf = (bf16*)alloc((size_t)2048 * 1024 * 2);
  bf16* Wrecb = (bf16*)alloc((size_t)2048 * 1024 * 2);
  bf16* attWtf = (bf16*)alloc((size_t)512 * 1024 * 2);
  bf16* attWtb = (bf16*)alloc((size_t)512 * 1024 * 2);
  bf16* ahW2f = (bf16*)alloc((size_t)512 * 1024 * 2);
  bf16* ahW2b = (bf16*)alloc((size_t)512 * 1024 * 2);
  bf16* Wh1f  = (bf16*)alloc((size_t)512 * 512 * 2);
  bf16* Wh1b  = (bf16*)alloc((size_t)512 * 512 * 2);
  bf16* Xpf   = (bf16*)alloc((size_t)2048 * 2048 * 2);
  bf16* Xpb   = (bf16*)alloc((size_t)2048 * 2048 * 2);
  bf16* Aff   = (bf16*)alloc((size_t)2048 * 512 * 2);
  bf16* Afb   = (bf16*)alloc((size_t)2048 * 512 * 2);
  bf16* Bmf   = (bf16*)alloc((size_t)2048 * 512 * 2);
  bf16* Bmb   = (bf16*)alloc((size_t)2048 * 512 * 2);
  float* c0f  = (float*)alloc(2048 * 4);
  float* c0b  = (float*)alloc(2048 * 4);
  bf16* hh0   = (bf16*)alloc((size_t)65 * 32 * 512 * 2);
  bf16* hh1   = (bf16*)alloc((size_t)65 * 32 * 512 * 2);
  bf16* hb0   = (bf16*)alloc((size_t)65 * 32 * 512 * 2);
  bf16* hb1   = (bf16*)alloc((size_t)65 * 32 * 512 * 2);
  bf16* Uf    = (bf16*)alloc((size_t)64 * 32 * 512 * 2);
  bf16* Ub    = (bf16*)alloc((size_t)64 * 32 * 512 * 2);
  float* cst0 = (float*)alloc((size_t)512 * 32 * 4);
  float* cst1 = (float*)alloc((size_t)512 * 32 * 4);

  hipMemsetAsync(d_ws, 0, zero_bytes, stream);

  k_xg<<<4096, 256, 0, stream>>>(emb, trg, xg);
  k_srcb<<<8192, 256, 0, stream>>>(src, srcb);
  k_fcw<<<8192, 256, 0, stream>>>(fcW, fcWb);
  k_wpack<<<2048, 256, 0, stream>>>(fWih, fWhh, bWih, bWhh, fattW, battW, bahW, fahW,
                                    Wxf, Wxb, Wrecf, Wrecb, attWtf, attWtb, ahW2f, ahW2b,
                                    Wh1f, Wh1b);
  k_c0<<<2048, 256, 0, stream>>>(src, fattb, battb, c0f, c0b);
  k_init<<<64, 256, 0, stream>>>(feed, hid, hh0, hh1, hb0, hb1, cst0, cst1);

  // Xp[gc][r] = (x @ Wih_x^T)^T  (gc-major so scan reads are b-coalesced)
  gemm_k<bf16, false><<<dim3(16, 16), 256, 0, stream>>>(Wxf, xg, Xpf, nullptr, 2048, 2048, 512);
  gemm_k<bf16, false><<<dim3(16, 16), 256, 0, stream>>>(Wxb, xg, Xpb, nullptr, 2048, 2048, 512);
  // A[r][j] = src @ attW ;  Bm[r][o] = src @ ahW_ct^T
  gemm_k<bf16, false><<<dim3(4, 16), 256, 0, stream>>>(srcb, attWtf, Aff, nullptr, 2048, 512, 1024);
  gemm_k<bf16, false><<<dim3(4, 16), 256, 0, stream>>>(srcb, attWtb, Afb, nullptr, 2048, 512, 1024);
  gemm_k<bf16, false><<<dim3(4, 16), 256, 0, stream>>>(srcb, ahW2f, Bmf, nullptr, 2048, 512, 1024);
  gemm_k<bf16, false><<<dim3(4, 16), 256, 0, stream>>>(srcb, ahW2b, Bmb, nullptr, 2048, 512, 1024);

  ScanP sp;
  sp.Wrec[0] = Wrecf; sp.Wrec[1] = Wrecb;
  sp.Xp[0] = Xpf;     sp.Xp[1] = Xpb;
  sp.Af[0] = Aff;     sp.Af[1] = Afb;
  sp.Bm[0] = Bmf;     sp.Bm[1] = Bmb;
  sp.Wh1[0] = Wh1f;   sp.Wh1[1] = Wh1b;
  sp.bih[0] = fbih;   sp.bih[1] = bbih;
  sp.bhh[0] = fbhh;   sp.bhh[1] = bbhh;
  sp.c0[0] = c0f;     sp.c0[1] = c0b;
  sp.ahb[0] = bahb;   sp.ahb[1] = fahb;   // att_hidden weights are swapped in the reference
  sp.mask = mask;
  sp.hh[0] = hh0;     sp.hh[1] = hh1;
  sp.hb[0] = hb0;     sp.hb[1] = hb1;
  sp.U[0] = Uf;       sp.U[1] = Ub;
  sp.cst[0] = cst0;   sp.cst[1] = cst1;
  sp.hcat = hcat;     sp.bar = bar;
  scan_k<<<64, 256, 0, stream>>>(sp);

  // logits[b*64+t][v] = hcat @ fcW^T + fcb
  gemm_k<float, true><<<dim3(250, 16), 256, 0, stream>>>(hcat, fcWb, (float*)d_out, fcb,
                                                         2048, 32000, 1024);
}